// Round 16
// baseline (157.151 us; speedup 1.0000x reference)
//
#include <hip/hip_runtime.h>
#include <cstdint>
#include <cstddef>

#define N_NODES 50000
#define N_EDGES 800000
#define IN_CH   64
#define OC      128   // HEADS*OUT_CH
#define HEADS   4
#define CH      32    // OUT_CH

#define NB      391        // buckets: 128 nodes each (n>>7); one set for dst, one for src
#define BCAP    2560       // per-bucket capacity (mean 2046, +11 sigma)
#define EPB     2048       // edges per hist block (256 threads x 8)
#define HIST_BLOCKS ((N_EDGES + EPB - 1) / EPB)   // 391

#define SENTINEL N_NODES   // dummy src node: a_src = -1e30 (weight->0), xh rows = 0
#define LST_LEN  (N_EDGES + 4 * N_NODES)   // padded CSR total (1,000,000)

typedef __attribute__((ext_vector_type(8))) short short8;   // 8 bf16 (4 VGPRs)
typedef __attribute__((ext_vector_type(4))) float f32x4;

static inline int ceil_div(int a, int b){ return (a + b - 1) / b; }

__device__ __forceinline__ float lrelu(float x){ return fmaxf(x, 0.2f * x); }

__device__ __forceinline__ float bf_lo(unsigned u){ return __uint_as_float(u << 16); }
__device__ __forceinline__ float bf_hi(unsigned u){ return __uint_as_float(u & 0xFFFF0000u); }

__device__ __forceinline__ unsigned pack_bf16(float x, float y){
  unsigned ux = __float_as_uint(x), uy = __float_as_uint(y);
  ux += 0x7FFFu + ((ux >> 16) & 1u);
  uy += 0x7FFFu + ((uy >> 16) & 1u);
  return (ux >> 16) | (uy & 0xFFFF0000u);   // low16 = x, high16 = y
}

// ---- K1 merged: blocks [0,HIST_BLOCKS) = LDS-staged bucket scatter;
//                 blocks [HIST_BLOCKS, +8) = Bh prep (bf16 frag-packed [W ; pe@W]) + inits.
__global__ __launch_bounds__(256) void k_hist_prep(const int* __restrict__ ei,
                                                   const int* __restrict__ et,
                                                   const float* __restrict__ pe,
                                                   const float* __restrict__ W,
                                                   unsigned* __restrict__ Bh,
                                                   int* __restrict__ btail,
                                                   unsigned* __restrict__ bbuf,
                                                   float* __restrict__ a_src,
                                                   unsigned* __restrict__ xh,
                                                   unsigned short* __restrict__ lst){
  __shared__ __align__(16) char smem[26816];
  int tid = threadIdx.x;

  if (blockIdx.x < HIST_BLOCKS){
    int* cnt  = (int*)smem;                       // 784
    int* lofs = cnt + 784;                        // 784
    int* gpos = lofs + 784;                       // 784
    unsigned* stage = (unsigned*)(gpos + 784);    // 4096 (16 KB)
    int* sred = (int*)(stage + 4096);             // 256

    for (int i = tid; i < 784; i += 256) cnt[i] = 0;
    __syncthreads();

    int e0 = blockIdx.x * EPB;
    unsigned ent[16];
    int rnk[16];
    short bck[16];
    #pragma unroll
    for (int j = 0; j < 8; ++j){
      int e = e0 + j * 256 + tid;
      bck[2 * j] = -1; bck[2 * j + 1] = -1;
      if (e < N_EDGES){
        int s = ei[e], d = ei[N_EDGES + e], t = et[e];
        int bd = d >> 7, bs = s >> 7;
        ent[2 * j]     = ((unsigned)bd << 23) | ((unsigned)(d & 127) << 16) | (unsigned)s;
        ent[2 * j + 1] = ((unsigned)bs << 23) | ((unsigned)(s & 127) << 16) | (unsigned)t;
        bck[2 * j]     = (short)bd;
        bck[2 * j + 1] = (short)(391 + bs);
        rnk[2 * j]     = atomicAdd(&cnt[bd], 1);
        rnk[2 * j + 1] = atomicAdd(&cnt[391 + bs], 1);
      }
    }
    __syncthreads();

    // exclusive scan of cnt[0..783]
    int v[4], pre[4], run = 0;
    #pragma unroll
    for (int i = 0; i < 4; ++i){
      int idx = tid * 4 + i;
      v[i] = (idx < 784) ? cnt[idx] : 0;
      pre[i] = run; run += v[i];
    }
    sred[tid] = run; __syncthreads();
    for (int off = 1; off < 256; off <<= 1){
      int t = (tid >= off) ? sred[tid - off] : 0;
      __syncthreads();
      sred[tid] += t;
      __syncthreads();
    }
    int toff = sred[tid] - run;
    #pragma unroll
    for (int i = 0; i < 4; ++i){
      int idx = tid * 4 + i;
      if (idx < 784) lofs[idx] = toff + pre[i];
    }
    __syncthreads();

    #pragma unroll
    for (int j = 0; j < 16; ++j){
      if (bck[j] >= 0) stage[lofs[bck[j]] + rnk[j]] = ent[j];
    }
    for (int b = tid; b < 782; b += 256){
      int c = cnt[b];
      gpos[b] = c ? atomicAdd(&btail[b], c) : 0;
    }
    __syncthreads();

    int totalD = lofs[391];
    int totalA = lofs[782];
    for (int i = tid; i < totalA; i += 256){
      unsigned e = stage[i];
      int b9 = (int)(e >> 23);
      int bc = (i < totalD) ? b9 : 391 + b9;
      int gp = gpos[bc] + (i - lofs[bc]);
      if (gp < BCAP) bbuf[(size_t)bc * BCAP + gp] = e;
    }
  } else {
    float* sPe  = (float*)smem;        // 64*64 (16 KB)
    float* sW64 = sPe + 4096;          // 64*16 [k][j]
    float* sPeW = sW64 + 1024;         // 64*16 [t][j]
    int nt = blockIdx.x - HIST_BLOCKS;
    int n0 = nt * 16;
    if (nt == 0){
      // zero sentinel message rows in all 4 head-blocked tables
      if (tid < 64)
        xh[((size_t)(tid >> 4) * (N_NODES + 1) + SENTINEL) * 16 + (tid & 15)] = 0;
      if (tid < 4)  a_src[SENTINEL * 4 + tid] = -1e30f;     // weight -> exp -> 0
      if (tid < 32) lst[LST_LEN + tid] = (unsigned short)SENTINEL;
    }
    for (int i = tid; i < 1024; i += 256)
      ((float4*)sPe)[i] = ((const float4*)pe)[i];
    for (int i = tid; i < 1024; i += 256){
      int k = i >> 4, j = i & 15;
      sW64[i] = W[k * 128 + n0 + j];
    }
    __syncthreads();
    for (int i = tid; i < 1024; i += 256){
      int t = i >> 4, j = i & 15;
      float a = 0.f;
      #pragma unroll
      for (int k = 0; k < 64; ++k) a += sPe[t * 64 + k] * sW64[k * 16 + j];
      sPeW[i] = a;
    }
    __syncthreads();
    for (int m = tid; m < 1024; m += 256){
      int j2 = m & 3, l = (m >> 2) & 63, kk = m >> 8;
      int k = kk * 32 + (l >> 4) * 8 + 2 * j2;   // even, pairs never straddle 64
      int jl = l & 15;
      float v0, v1;
      if (k < 64){ v0 = sW64[k * 16 + jl]; v1 = sW64[(k + 1) * 16 + jl]; }
      else       { v0 = sPeW[(k - 64) * 16 + jl]; v1 = sPeW[(k - 63) * 16 + jl]; }
      Bh[nt * 1024 + m] = pack_bf16(v0, v1);
    }
  }
}

// ---- merged pass B + fused MFMA GEMM ----
// blocks [0,NB): dst buckets -> padded row_dst + u16 lst (+4 sentinels per node)
// blocks [NB,2NB): src buckets -> LDS type-hist -> MFMA GEMM for 128 rows
//                  -> a_src/a_dst + head-blocked xh
__global__ __launch_bounds__(256) void k_passB(const unsigned* __restrict__ bbuf,
                                               const int* __restrict__ btail,
                                               int* __restrict__ row_dst,
                                               unsigned short* __restrict__ lst,
                                               const float* __restrict__ x,
                                               const unsigned* __restrict__ Bh,
                                               const float* __restrict__ att_s,
                                               const float* __restrict__ att_d,
                                               float* __restrict__ a_src,
                                               float* __restrict__ a_dst,
                                               unsigned* __restrict__ xh){
  int g = blockIdx.x, tid = threadIdx.x;
  if (g < NB){
    __shared__ int cnt[128], sc[128], cur[128], red[256];
    __shared__ int sbase;
    int d0 = g << 7;
    int nn = min(128, N_NODES - d0);
    int cnt_b = min(btail[g], BCAP);
    int part = 0;
    for (int q = tid; q < g; q += 256) part += min(btail[q], BCAP);
    red[tid] = part; __syncthreads();
    for (int off = 128; off > 0; off >>= 1){
      if (tid < off) red[tid] += red[tid + off];
      __syncthreads();
    }
    if (tid == 0) sbase = red[0];
    if (tid < 128) cnt[tid] = 0;
    __syncthreads();
    int base0 = sbase + 4 * d0;   // padded base (+4 slots per preceding node)
    for (int i = tid; i < cnt_b; i += 256)
      atomicAdd(&cnt[(bbuf[(size_t)g * BCAP + i] >> 16) & 127], 1);
    __syncthreads();
    if (tid < 128) sc[tid] = cnt[tid];
    __syncthreads();
    for (int off = 1; off < 128; off <<= 1){
      int t = (tid < 128 && tid >= off) ? sc[tid - off] : 0;
      __syncthreads();
      if (tid < 128) sc[tid] += t;
      __syncthreads();
    }
    if (tid < nn){
      int ex = sc[tid] - cnt[tid];
      cur[tid] = ex + 4 * tid;
      row_dst[d0 + tid] = base0 + ex + 4 * tid;
    }
    if (g == NB - 1 && tid == 0) row_dst[N_NODES] = base0 + cnt_b + 4 * nn;
    __syncthreads();
    for (int i = tid; i < cnt_b; i += 256){
      unsigned e = bbuf[(size_t)g * BCAP + i];
      int p = atomicAdd(&cur[(e >> 16) & 127], 1);
      lst[base0 + p] = (unsigned short)(e & 0xFFFFu);
    }
    __syncthreads();
    if (tid < nn){
      int pe_ = cur[tid];
      #pragma unroll
      for (int k = 0; k < 4; ++k) lst[base0 + pe_ + k] = (unsigned short)SENTINEL;
    }
  } else {
    __shared__ unsigned hist[128 * 16];   // u8-packed per-node type counts, 8 KB
    __shared__ unsigned sB[8192];         // frag-packed B, 32 KB
    __shared__ unsigned sA[4096];         // 64 rows x 128 k bf16, swizzled, 16 KB
    int n0 = (g - NB) << 7;
    for (int i = tid; i < 2048; i += 256) hist[i] = 0;
    __syncthreads();
    int cnt_b = min(btail[g], BCAP);
    for (int i = tid; i < cnt_b; i += 256){
      unsigned e = bbuf[(size_t)g * BCAP + i];
      unsigned t = e & 63u;
      atomicAdd(&hist[((e >> 16) & 127) * 16 + (t >> 2)], 1u << (8 * (t & 3)));
    }
    {
      const uint4* srcp = (const uint4*)Bh;
      uint4* dstp = (uint4*)sB;
      #pragma unroll
      for (int i = 0; i < 8; ++i) dstp[tid + i * 256] = srcp[tid + i * 256];
    }
    __syncthreads();

    int wid = tid >> 6, l = tid & 63;
    int c15 = l & 15, kq = l >> 4;
    float asv[8], adv[8];
    #pragma unroll
    for (int nt = 0; nt < 8; ++nt){
      asv[nt] = att_s[nt * 16 + c15];
      adv[nt] = att_d[nt * 16 + c15];
    }

    for (int half = 0; half < 2; ++half){
      int row0 = n0 + half * 64;
      {
        int r = tid >> 2, q = tid & 3;
        int n = row0 + r;
        unsigned swz = (unsigned)((r & 7) << 4);
        float4 xv[4];
        if (n < N_NODES){
          const float4* xr = (const float4*)(x + (size_t)n * 64);
          #pragma unroll
          for (int i = 0; i < 4; ++i) xv[i] = xr[q * 4 + i];
        } else {
          #pragma unroll
          for (int i = 0; i < 4; ++i) xv[i] = make_float4(0.f, 0.f, 0.f, 0.f);
        }
        unsigned pk[8];
        #pragma unroll
        for (int i = 0; i < 4; ++i){
          pk[2 * i]     = pack_bf16(xv[i].x, xv[i].y);
          pk[2 * i + 1] = pack_bf16(xv[i].z, xv[i].w);
        }
        unsigned b0 = (unsigned)(r * 256 + q * 32);
        *(uint4*)(sA + (((b0)      ^ swz) >> 2)) = make_uint4(pk[0], pk[1], pk[2], pk[3]);
        *(uint4*)(sA + (((b0 + 16) ^ swz) >> 2)) = make_uint4(pk[4], pk[5], pk[6], pk[7]);
        unsigned cw[4];
        #pragma unroll
        for (int i = 0; i < 4; ++i) cw[i] = hist[(half * 64 + r) * 16 + q * 4 + i];
        unsigned pc[8];
        #pragma unroll
        for (int i = 0; i < 4; ++i){
          unsigned w = cw[i];
          pc[2 * i]     = pack_bf16((float)(w & 0xFFu), (float)((w >> 8) & 0xFFu));
          pc[2 * i + 1] = pack_bf16((float)((w >> 16) & 0xFFu), (float)(w >> 24));
        }
        unsigned b1 = (unsigned)(r * 256 + 128 + q * 32);
        *(uint4*)(sA + (((b1)      ^ swz) >> 2)) = make_uint4(pc[0], pc[1], pc[2], pc[3]);
        *(uint4*)(sA + (((b1 + 16) ^ swz) >> 2)) = make_uint4(pc[4], pc[5], pc[6], pc[7]);
      }
      __syncthreads();

      int arow = wid * 16 + c15;
      f32x4 acc[8];
      #pragma unroll
      for (int nt = 0; nt < 8; ++nt) acc[nt] = (f32x4){0.f, 0.f, 0.f, 0.f};
      #pragma unroll
      for (int kk = 0; kk < 4; ++kk){
        unsigned abyte = (unsigned)(arow * 256 + kk * 64 + kq * 16);
        abyte ^= (unsigned)((arow & 7) << 4);
        short8 af = *(const short8*)((const char*)sA + abyte);
        #pragma unroll
        for (int nt = 0; nt < 8; ++nt){
          short8 bf = *(const short8*)(sB + (size_t)((nt * 4 + kk) * 64 + l) * 4);
          acc[nt] = __builtin_amdgcn_mfma_f32_16x16x32_bf16(af, bf, acc[nt], 0, 0, 0);
        }
      }

      #pragma unroll
      for (int r = 0; r < 4; ++r){
        int row = row0 + wid * 16 + kq * 4 + r;
        bool valid = row < N_NODES;
        #pragma unroll
        for (int h = 0; h < 4; ++h){
          float ps = acc[2 * h][r] * asv[2 * h] + acc[2 * h + 1][r] * asv[2 * h + 1];
          float pd = acc[2 * h][r] * adv[2 * h] + acc[2 * h + 1][r] * adv[2 * h + 1];
          #pragma unroll
          for (int m = 1; m < 16; m <<= 1){
            ps += __shfl_xor(ps, m);
            pd += __shfl_xor(pd, m);
          }
          if (valid && c15 == 0){
            a_src[row * 4 + h] = ps;
            a_dst[row * 4 + h] = pd;
          }
        }
        #pragma unroll
        for (int nt = 0; nt < 8; ++nt){
          float own = acc[nt][r];
          float nb = __shfl_xor(own, 1);
          if (valid && !(c15 & 1)){
            // head-blocked: table h = nt>>1, pair = (nt&1)*8 + c15/2
            int hh = nt >> 1;
            int pair = (nt & 1) * 8 + (c15 >> 1);
            xh[((size_t)hh * (N_NODES + 1) + row) * 16 + pair] = pack_bf16(own, nb);
          }
        }
      }
      __syncthreads();
    }
  }
}

// ---- fused aggregate: per-head passes over 3.2MB L2-resident table slices ----
// wave per node; slot = l>>4 (edge in group of 4), c = l&15 (channel pair of head h).
__global__ __launch_bounds__(256) void k_aggregate(const int* __restrict__ row_dst,
                                                   const unsigned short* __restrict__ lst,
                                                   const float* __restrict__ a_src,
                                                   const float* __restrict__ a_dst,
                                                   const unsigned* __restrict__ xh,
                                                   const float* __restrict__ bias,
                                                   float* __restrict__ out){
  int n = (blockIdx.x * blockDim.x + threadIdx.x) >> 6;
  if (n >= N_NODES) return;
  int l = threadIdx.x & 63;
  int slot = l >> 4;
  int c = l & 15;

  int k0 = row_dst[n];
  int k1 = row_dst[n + 1] - 4;   // real-edge end; [k1, k1+4) are sentinels

  float4 ad4 = *(const float4*)(a_dst + (size_t)n * 4);
  float4 as4 = *(const float4*)(a_src + (size_t)n * 4);
  float advs[4] = {ad4.x, ad4.y, ad4.z, ad4.w};
  float asvs[4] = {as4.x, as4.y, as4.z, as4.w};

  #pragma unroll
  for (int h = 0; h < 4; ++h){
    const unsigned* T = xh + (size_t)h * (N_NODES + 1) * 16;
    float ad = advs[h];

    // self loop (slot 0 contributes)
    float wself = __expf(lrelu(asvs[h] + ad));
    unsigned uv = T[(size_t)n * 16 + c];
    float lp = 0.f, ax = 0.f, ay = 0.f;
    if (slot == 0){
      lp = wself;
      ax = wself * bf_lo(uv);
      ay = wself * bf_hi(uv);
    }

    #define LOADG(U, B, base) {                     \
      int t_ = (int)lst[(base) + slot];             \
      U = T[(size_t)t_ * 16 + c];                   \
      B = a_src[t_ * 4 + h]; }
    #define PROCG(U, B) {                           \
      float w_ = __expf(lrelu((B) + ad));           \
      lp += w_;                                     \
      ax = fmaf(w_, bf_lo(U), ax);                  \
      ay = fmaf(w_, bf_hi(U), ay); }

    if (k0 < k1){
      unsigned u0 = 0, u1 = 0, u2 = 0, u3 = 0;
      float b0 = -1e30f, b1 = -1e30f, b2 = -1e30f, b3 = -1e30f;
      int j = k0;
      LOADG(u0, b0, j);
      if (j + 4  < k1) LOADG(u1, b1, j + 4);
      if (j + 8  < k1) LOADG(u2, b2, j + 8);
      if (j + 12 < k1) LOADG(u3, b3, j + 12);
      for (;;){
        PROCG(u0, b0);
        j += 4; if (j >= k1) break;
        if (j + 12 < k1) LOADG(u0, b0, j + 12);
        PROCG(u1, b1);
        j += 4; if (j >= k1) break;
        if (j + 12 < k1) LOADG(u1, b1, j + 12);
        PROCG(u2, b2);
        j += 4; if (j >= k1) break;
        if (j + 12 < k1) LOADG(u2, b2, j + 12);
        PROCG(u3, b3);
        j += 4; if (j >= k1) break;
        if (j + 12 < k1) LOADG(u3, b3, j + 12);
      }
    }
    #undef LOADG
    #undef PROCG

    // reduce across the 4 edge-slots (lanes with same c)
    lp += __shfl_xor(lp, 16); lp += __shfl_xor(lp, 32);
    ax += __shfl_xor(ax, 16); ax += __shfl_xor(ax, 32);
    ay += __shfl_xor(ay, 16); ay += __shfl_xor(ay, 32);

    if (slot == 0){
      float inv = 1.f / lp;
      float2 bb = ((const float2*)bias)[h * 16 + c];
      float r0 = ax * inv + bb.x;
      float r1 = ay * inv + bb.y;
      float2 o;
      o.x = r0 > 0.f ? r0 : expm1f(r0);
      o.y = r1 > 0.f ? r1 : expm1f(r1);
      ((float2*)out)[(size_t)n * 64 + h * 16 + c] = o;
    }
  }
}

extern "C" void kernel_launch(void* const* d_in, const int* in_sizes, int n_in,
                              void* d_out, int out_size, void* d_ws, size_t ws_size,
                              hipStream_t stream){
  const float* x     = (const float*)d_in[0];
  const int*   ei    = (const int*)d_in[1];   // [2, E]
  const int*   et    = (const int*)d_in[2];   // [E]
  const float* pe    = (const float*)d_in[3];
  const float* W     = (const float*)d_in[4];
  const float* att_s = (const float*)d_in[5];
  const float* att_d = (const float*)d_in[6];
  const float* bias  = (const float*)d_in[7];
  float* out = (float*)d_out;

  // workspace carve-up (4-byte units)
  int*      btail   = (int*)d_ws;                                  // 2*NB (pad 1024)
  int*      row_dst = btail + 1024;                                // N+1 (pad 8)
  unsigned* Bh      = (unsigned*)(row_dst + N_NODES + 8);          // 8192
  float*    a_src   = (float*)(Bh + 8192);                         // (N+1)*4 (sentinel row)
  float*    a_dst   = a_src + (size_t)(N_NODES + 1) * 4;           // N*4
  unsigned* xh      = (unsigned*)(a_dst + (size_t)N_NODES * 4);    // 4 head tables x (N+1)*16
  unsigned* bbuf    = xh + (size_t)4 * (N_NODES + 1) * 16;         // 2*NB*BCAP
  unsigned short* lst = (unsigned short*)(bbuf + (size_t)2 * NB * BCAP); // LST_LEN+32 u16

  const int B = 256;

  hipMemsetAsync(btail, 0, 1024 * sizeof(int), stream);
  k_hist_prep<<<HIST_BLOCKS + 8, B, 0, stream>>>(ei, et, pe, W, Bh, btail, bbuf,
                                                 a_src, xh, lst);
  k_passB<<<2 * NB, B, 0, stream>>>(bbuf, btail, row_dst, lst,
                                    x, Bh, att_s, att_d, a_src, a_dst, xh);
  k_aggregate<<<ceil_div(N_NODES * 64, B), B, 0, stream>>>(row_dst, lst, a_src, a_dst,
                                                           xh, bias, out);
}

// Round 17
// 95.636 us; speedup vs baseline: 1.6432x; 1.6432x over previous
//
#include <hip/hip_runtime.h>
#include <cstdint>
#include <cstddef>

#define N_NODES 50000
#define N_EDGES 800000
#define IN_CH   64
#define OC      128   // HEADS*OUT_CH
#define HEADS   4
#define CH      32    // OUT_CH

#define NB      391        // buckets: 128 nodes each (n>>7); one set for dst, one for src
#define BCAP    2560       // per-bucket capacity (mean 2046, +11 sigma)
#define EPB     2048       // edges per hist block (256 threads x 8)
#define HIST_BLOCKS ((N_EDGES + EPB - 1) / EPB)   // 391

#define SENTINEL N_NODES   // dummy src node: a_src = -1e30 (weight->0), xh row = 0
#define LST_LEN  (N_EDGES + 4 * N_NODES)   // padded CSR total (1,000,000)

typedef __attribute__((ext_vector_type(8))) short short8;   // 8 bf16 (4 VGPRs)
typedef __attribute__((ext_vector_type(4))) float f32x4;

static inline int ceil_div(int a, int b){ return (a + b - 1) / b; }

__device__ __forceinline__ float lrelu(float x){ return fmaxf(x, 0.2f * x); }

__device__ __forceinline__ float bf_lo(unsigned u){ return __uint_as_float(u << 16); }
__device__ __forceinline__ float bf_hi(unsigned u){ return __uint_as_float(u & 0xFFFF0000u); }

__device__ __forceinline__ unsigned pack_bf16(float x, float y){
  unsigned ux = __float_as_uint(x), uy = __float_as_uint(y);
  ux += 0x7FFFu + ((ux >> 16) & 1u);
  uy += 0x7FFFu + ((uy >> 16) & 1u);
  return (ux >> 16) | (uy & 0xFFFF0000u);   // low16 = x, high16 = y
}

// ---- K1 merged: blocks [0,HIST_BLOCKS) = LDS-staged bucket scatter;
//                 blocks [HIST_BLOCKS, +8) = Bh prep (bf16 frag-packed [W ; pe@W]) + inits.
__global__ __launch_bounds__(256) void k_hist_prep(const int* __restrict__ ei,
                                                   const int* __restrict__ et,
                                                   const float* __restrict__ pe,
                                                   const float* __restrict__ W,
                                                   unsigned* __restrict__ Bh,
                                                   int* __restrict__ btail,
                                                   unsigned* __restrict__ bbuf,
                                                   float* __restrict__ a_src,
                                                   unsigned* __restrict__ xh,
                                                   unsigned short* __restrict__ lst){
  __shared__ __align__(16) char smem[26816];
  int tid = threadIdx.x;

  if (blockIdx.x < HIST_BLOCKS){
    int* cnt  = (int*)smem;                       // 784
    int* lofs = cnt + 784;                        // 784
    int* gpos = lofs + 784;                       // 784
    unsigned* stage = (unsigned*)(gpos + 784);    // 4096 (16 KB)
    int* sred = (int*)(stage + 4096);             // 256

    for (int i = tid; i < 784; i += 256) cnt[i] = 0;
    __syncthreads();

    int e0 = blockIdx.x * EPB;
    unsigned ent[16];
    int rnk[16];
    short bck[16];
    #pragma unroll
    for (int j = 0; j < 8; ++j){
      int e = e0 + j * 256 + tid;
      bck[2 * j] = -1; bck[2 * j + 1] = -1;
      if (e < N_EDGES){
        int s = ei[e], d = ei[N_EDGES + e], t = et[e];
        int bd = d >> 7, bs = s >> 7;
        ent[2 * j]     = ((unsigned)bd << 23) | ((unsigned)(d & 127) << 16) | (unsigned)s;
        ent[2 * j + 1] = ((unsigned)bs << 23) | ((unsigned)(s & 127) << 16) | (unsigned)t;
        bck[2 * j]     = (short)bd;
        bck[2 * j + 1] = (short)(391 + bs);
        rnk[2 * j]     = atomicAdd(&cnt[bd], 1);
        rnk[2 * j + 1] = atomicAdd(&cnt[391 + bs], 1);
      }
    }
    __syncthreads();

    // exclusive scan of cnt[0..783]
    int v[4], pre[4], run = 0;
    #pragma unroll
    for (int i = 0; i < 4; ++i){
      int idx = tid * 4 + i;
      v[i] = (idx < 784) ? cnt[idx] : 0;
      pre[i] = run; run += v[i];
    }
    sred[tid] = run; __syncthreads();
    for (int off = 1; off < 256; off <<= 1){
      int t = (tid >= off) ? sred[tid - off] : 0;
      __syncthreads();
      sred[tid] += t;
      __syncthreads();
    }
    int toff = sred[tid] - run;
    #pragma unroll
    for (int i = 0; i < 4; ++i){
      int idx = tid * 4 + i;
      if (idx < 784) lofs[idx] = toff + pre[i];
    }
    __syncthreads();

    #pragma unroll
    for (int j = 0; j < 16; ++j){
      if (bck[j] >= 0) stage[lofs[bck[j]] + rnk[j]] = ent[j];
    }
    for (int b = tid; b < 782; b += 256){
      int c = cnt[b];
      gpos[b] = c ? atomicAdd(&btail[b], c) : 0;
    }
    __syncthreads();

    int totalD = lofs[391];
    int totalA = lofs[782];
    for (int i = tid; i < totalA; i += 256){
      unsigned e = stage[i];
      int b9 = (int)(e >> 23);
      int bc = (i < totalD) ? b9 : 391 + b9;
      int gp = gpos[bc] + (i - lofs[bc]);
      if (gp < BCAP) bbuf[(size_t)bc * BCAP + gp] = e;
    }
  } else {
    float* sPe  = (float*)smem;        // 64*64 (16 KB)
    float* sW64 = sPe + 4096;          // 64*16 [k][j]
    float* sPeW = sW64 + 1024;         // 64*16 [t][j]
    int nt = blockIdx.x - HIST_BLOCKS;
    int n0 = nt * 16;
    if (nt == 0){
      if (tid < 64) xh[(size_t)SENTINEL * 64 + tid] = 0;    // zero sentinel message row
      if (tid < 4)  a_src[SENTINEL * 4 + tid] = -1e30f;     // weight -> exp -> 0
      if (tid < 32) lst[LST_LEN + tid] = (unsigned short)SENTINEL;
    }
    for (int i = tid; i < 1024; i += 256)
      ((float4*)sPe)[i] = ((const float4*)pe)[i];
    for (int i = tid; i < 1024; i += 256){
      int k = i >> 4, j = i & 15;
      sW64[i] = W[k * 128 + n0 + j];
    }
    __syncthreads();
    for (int i = tid; i < 1024; i += 256){
      int t = i >> 4, j = i & 15;
      float a = 0.f;
      #pragma unroll
      for (int k = 0; k < 64; ++k) a += sPe[t * 64 + k] * sW64[k * 16 + j];
      sPeW[i] = a;
    }
    __syncthreads();
    for (int m = tid; m < 1024; m += 256){
      int j2 = m & 3, l = (m >> 2) & 63, kk = m >> 8;
      int k = kk * 32 + (l >> 4) * 8 + 2 * j2;   // even, pairs never straddle 64
      int jl = l & 15;
      float v0, v1;
      if (k < 64){ v0 = sW64[k * 16 + jl]; v1 = sW64[(k + 1) * 16 + jl]; }
      else       { v0 = sPeW[(k - 64) * 16 + jl]; v1 = sPeW[(k - 63) * 16 + jl]; }
      Bh[nt * 1024 + m] = pack_bf16(v0, v1);
    }
  }
}

// ---- merged pass B + fused MFMA GEMM ----
// blocks [0,NB): dst buckets -> padded row_dst + u16 lst (+4 sentinels per node)
// blocks [NB,2NB): src buckets -> LDS type-hist -> MFMA GEMM for 128 rows
//                  -> a_src/a_dst/xh directly
__global__ __launch_bounds__(256) void k_passB(const unsigned* __restrict__ bbuf,
                                               const int* __restrict__ btail,
                                               int* __restrict__ row_dst,
                                               unsigned short* __restrict__ lst,
                                               const float* __restrict__ x,
                                               const unsigned* __restrict__ Bh,
                                               const float* __restrict__ att_s,
                                               const float* __restrict__ att_d,
                                               float* __restrict__ a_src,
                                               float* __restrict__ a_dst,
                                               unsigned* __restrict__ xh){
  int g = blockIdx.x, tid = threadIdx.x;
  if (g < NB){
    __shared__ int cnt[128], sc[128], cur[128], red[256];
    __shared__ int sbase;
    int d0 = g << 7;
    int nn = min(128, N_NODES - d0);
    int cnt_b = min(btail[g], BCAP);
    int part = 0;
    for (int q = tid; q < g; q += 256) part += min(btail[q], BCAP);
    red[tid] = part; __syncthreads();
    for (int off = 128; off > 0; off >>= 1){
      if (tid < off) red[tid] += red[tid + off];
      __syncthreads();
    }
    if (tid == 0) sbase = red[0];
    if (tid < 128) cnt[tid] = 0;
    __syncthreads();
    int base0 = sbase + 4 * d0;   // padded base (+4 slots per preceding node)
    for (int i = tid; i < cnt_b; i += 256)
      atomicAdd(&cnt[(bbuf[(size_t)g * BCAP + i] >> 16) & 127], 1);
    __syncthreads();
    if (tid < 128) sc[tid] = cnt[tid];
    __syncthreads();
    for (int off = 1; off < 128; off <<= 1){
      int t = (tid < 128 && tid >= off) ? sc[tid - off] : 0;
      __syncthreads();
      if (tid < 128) sc[tid] += t;
      __syncthreads();
    }
    if (tid < nn){
      int ex = sc[tid] - cnt[tid];
      cur[tid] = ex + 4 * tid;
      row_dst[d0 + tid] = base0 + ex + 4 * tid;
    }
    if (g == NB - 1 && tid == 0) row_dst[N_NODES] = base0 + cnt_b + 4 * nn;
    __syncthreads();
    for (int i = tid; i < cnt_b; i += 256){
      unsigned e = bbuf[(size_t)g * BCAP + i];
      int p = atomicAdd(&cur[(e >> 16) & 127], 1);
      lst[base0 + p] = (unsigned short)(e & 0xFFFFu);
    }
    __syncthreads();
    if (tid < nn){
      int pe_ = cur[tid];
      #pragma unroll
      for (int k = 0; k < 4; ++k) lst[base0 + pe_ + k] = (unsigned short)SENTINEL;
    }
  } else {
    __shared__ unsigned hist[128 * 16];   // u8-packed per-node type counts, 8 KB
    __shared__ unsigned sB[8192];         // frag-packed B, 32 KB
    __shared__ unsigned sA[4096];         // 64 rows x 128 k bf16, swizzled, 16 KB
    int n0 = (g - NB) << 7;
    for (int i = tid; i < 2048; i += 256) hist[i] = 0;
    __syncthreads();
    int cnt_b = min(btail[g], BCAP);
    for (int i = tid; i < cnt_b; i += 256){
      unsigned e = bbuf[(size_t)g * BCAP + i];
      unsigned t = e & 63u;
      atomicAdd(&hist[((e >> 16) & 127) * 16 + (t >> 2)], 1u << (8 * (t & 3)));
    }
    {
      const uint4* srcp = (const uint4*)Bh;
      uint4* dstp = (uint4*)sB;
      #pragma unroll
      for (int i = 0; i < 8; ++i) dstp[tid + i * 256] = srcp[tid + i * 256];
    }
    __syncthreads();

    int wid = tid >> 6, l = tid & 63;
    int c15 = l & 15, kq = l >> 4;
    float asv[8], adv[8];
    #pragma unroll
    for (int nt = 0; nt < 8; ++nt){
      asv[nt] = att_s[nt * 16 + c15];
      adv[nt] = att_d[nt * 16 + c15];
    }

    for (int half = 0; half < 2; ++half){
      int row0 = n0 + half * 64;
      {
        int r = tid >> 2, q = tid & 3;
        int n = row0 + r;
        unsigned swz = (unsigned)((r & 7) << 4);
        float4 xv[4];
        if (n < N_NODES){
          const float4* xr = (const float4*)(x + (size_t)n * 64);
          #pragma unroll
          for (int i = 0; i < 4; ++i) xv[i] = xr[q * 4 + i];
        } else {
          #pragma unroll
          for (int i = 0; i < 4; ++i) xv[i] = make_float4(0.f, 0.f, 0.f, 0.f);
        }
        unsigned pk[8];
        #pragma unroll
        for (int i = 0; i < 4; ++i){
          pk[2 * i]     = pack_bf16(xv[i].x, xv[i].y);
          pk[2 * i + 1] = pack_bf16(xv[i].z, xv[i].w);
        }
        unsigned b0 = (unsigned)(r * 256 + q * 32);
        *(uint4*)(sA + (((b0)      ^ swz) >> 2)) = make_uint4(pk[0], pk[1], pk[2], pk[3]);
        *(uint4*)(sA + (((b0 + 16) ^ swz) >> 2)) = make_uint4(pk[4], pk[5], pk[6], pk[7]);
        unsigned cw[4];
        #pragma unroll
        for (int i = 0; i < 4; ++i) cw[i] = hist[(half * 64 + r) * 16 + q * 4 + i];
        unsigned pc[8];
        #pragma unroll
        for (int i = 0; i < 4; ++i){
          unsigned w = cw[i];
          pc[2 * i]     = pack_bf16((float)(w & 0xFFu), (float)((w >> 8) & 0xFFu));
          pc[2 * i + 1] = pack_bf16((float)((w >> 16) & 0xFFu), (float)(w >> 24));
        }
        unsigned b1 = (unsigned)(r * 256 + 128 + q * 32);
        *(uint4*)(sA + (((b1)      ^ swz) >> 2)) = make_uint4(pc[0], pc[1], pc[2], pc[3]);
        *(uint4*)(sA + (((b1 + 16) ^ swz) >> 2)) = make_uint4(pc[4], pc[5], pc[6], pc[7]);
      }
      __syncthreads();

      int arow = wid * 16 + c15;
      f32x4 acc[8];
      #pragma unroll
      for (int nt = 0; nt < 8; ++nt) acc[nt] = (f32x4){0.f, 0.f, 0.f, 0.f};
      #pragma unroll
      for (int kk = 0; kk < 4; ++kk){
        unsigned abyte = (unsigned)(arow * 256 + kk * 64 + kq * 16);
        abyte ^= (unsigned)((arow & 7) << 4);
        short8 af = *(const short8*)((const char*)sA + abyte);
        #pragma unroll
        for (int nt = 0; nt < 8; ++nt){
          short8 bf = *(const short8*)(sB + (size_t)((nt * 4 + kk) * 64 + l) * 4);
          acc[nt] = __builtin_amdgcn_mfma_f32_16x16x32_bf16(af, bf, acc[nt], 0, 0, 0);
        }
      }

      #pragma unroll
      for (int r = 0; r < 4; ++r){
        int row = row0 + wid * 16 + kq * 4 + r;
        bool valid = row < N_NODES;
        #pragma unroll
        for (int h = 0; h < 4; ++h){
          float ps = acc[2 * h][r] * asv[2 * h] + acc[2 * h + 1][r] * asv[2 * h + 1];
          float pd = acc[2 * h][r] * adv[2 * h] + acc[2 * h + 1][r] * adv[2 * h + 1];
          #pragma unroll
          for (int m = 1; m < 16; m <<= 1){
            ps += __shfl_xor(ps, m);
            pd += __shfl_xor(pd, m);
          }
          if (valid && c15 == 0){
            a_src[row * 4 + h] = ps;
            a_dst[row * 4 + h] = pd;
          }
        }
        #pragma unroll
        for (int nt = 0; nt < 8; ++nt){
          float own = acc[nt][r];
          float nb = __shfl_xor(own, 1);
          if (valid && !(c15 & 1))
            xh[(size_t)row * 64 + nt * 8 + (c15 >> 1)] = pack_bf16(own, nb);
        }
      }
      __syncthreads();
    }
  }
}

// ---- fused aggregate: guardless padded CSR, 8-deep two-bank pipeline ----
// wave per node; lane l owns channels (2l, 2l+1) as bf16x2; head h = l>>4.
__global__ __launch_bounds__(256) void k_aggregate(const int* __restrict__ row_dst,
                                                   const unsigned short* __restrict__ lst,
                                                   const float* __restrict__ a_src,
                                                   const float* __restrict__ a_dst,
                                                   const unsigned* __restrict__ xh,
                                                   const float* __restrict__ bias,
                                                   float* __restrict__ out){
  int n = (blockIdx.x * blockDim.x + threadIdx.x) >> 6;
  if (n >= N_NODES) return;
  int l = threadIdx.x & 63;
  int h = l >> 4;
  float ad = a_dst[n * 4 + h];

  // self loop
  float w = __expf(lrelu(a_src[n * 4 + h] + ad));
  unsigned uv = xh[(size_t)n * 64 + l];
  float l0 = w, l1 = 0.f, l2 = 0.f, l3 = 0.f;
  float a0x = w * bf_lo(uv), a0y = w * bf_hi(uv);
  float a1x = 0.f, a1y = 0.f, a2x = 0.f, a2y = 0.f, a3x = 0.f, a3y = 0.f;

  int k0 = row_dst[n];
  int k1 = row_dst[n + 1] - 4;   // real-edge end; [k1, k1+4) are sentinels

  #define LOADB(U0,B0,U1,B1,U2,B2,U3,B3, base) {                          \
    int t0 = (int)lst[(base)],     t1 = (int)lst[(base) + 1];             \
    int t2 = (int)lst[(base) + 2], t3 = (int)lst[(base) + 3];             \
    U0 = xh[(size_t)t0 * 64 + l];  B0 = a_src[t0 * 4 + h];                \
    U1 = xh[(size_t)t1 * 64 + l];  B1 = a_src[t1 * 4 + h];                \
    U2 = xh[(size_t)t2 * 64 + l];  B2 = a_src[t2 * 4 + h];                \
    U3 = xh[(size_t)t3 * 64 + l];  B3 = a_src[t3 * 4 + h];                \
  }
  #define PROC4(U0,B0,U1,B1,U2,B2,U3,B3) {                                \
    float w0 = __expf(lrelu(B0 + ad));                                    \
    l0 += w0; a0x = fmaf(w0, bf_lo(U0), a0x); a0y = fmaf(w0, bf_hi(U0), a0y); \
    float w1 = __expf(lrelu(B1 + ad));                                    \
    l1 += w1; a1x = fmaf(w1, bf_lo(U1), a1x); a1y = fmaf(w1, bf_hi(U1), a1y); \
    float w2 = __expf(lrelu(B2 + ad));                                    \
    l2 += w2; a2x = fmaf(w2, bf_lo(U2), a2x); a2y = fmaf(w2, bf_hi(U2), a2y); \
    float w3 = __expf(lrelu(B3 + ad));                                    \
    l3 += w3; a3x = fmaf(w3, bf_lo(U3), a3x); a3y = fmaf(w3, bf_hi(U3), a3y); \
  }

  unsigned uA0, uA1, uA2, uA3, uB0, uB1, uB2, uB3, n0_, n1_, n2_, n3_;
  float bA0, bA1, bA2, bA3, bB0, bB1, bB2, bB3, f0_, f1_, f2_, f3_;

  if (k0 < k1){
    int j = k0;
    LOADB(uA0,bA0, uA1,bA1, uA2,bA2, uA3,bA3, j);       // bank A: [j, j+4)
    LOADB(uB0,bB0, uB1,bB1, uB2,bB2, uB3,bB3, j + 4);   // bank B: [j+4, j+8)
    for (;;){
      LOADB(n0_,f0_, n1_,f1_, n2_,f2_, n3_,f3_, j + 8);
      PROC4(uA0,bA0, uA1,bA1, uA2,bA2, uA3,bA3);
      uA0 = n0_; bA0 = f0_; uA1 = n1_; bA1 = f1_;
      uA2 = n2_; bA2 = f2_; uA3 = n3_; bA3 = f3_;
      j += 4;
      if (j >= k1) break;
      LOADB(n0_,f0_, n1_,f1_, n2_,f2_, n3_,f3_, j + 8);
      PROC4(uB0,bB0, uB1,bB1, uB2,bB2, uB3,bB3);
      uB0 = n0_; bB0 = f0_; uB1 = n1_; bB1 = f1_;
      uB2 = n2_; bB2 = f2_; uB3 = n3_; bB3 = f3_;
      j += 4;
      if (j >= k1) break;
    }
  }
  #undef LOADB
  #undef PROC4

  float lsum = (l0 + l1) + (l2 + l3);
  float accx = (a0x + a1x) + (a2x + a3x);
  float accy = (a0y + a1y) + (a2y + a3y);
  float2 b = ((const float2*)bias)[l];
  float r0 = accx / lsum + b.x;
  float r1 = accy / lsum + b.y;
  float2 o;
  o.x = r0 > 0.f ? r0 : expm1f(r0);
  o.y = r1 > 0.f ? r1 : expm1f(r1);
  ((float2*)out)[(size_t)n * 64 + l] = o;
}

extern "C" void kernel_launch(void* const* d_in, const int* in_sizes, int n_in,
                              void* d_out, int out_size, void* d_ws, size_t ws_size,
                              hipStream_t stream){
  const float* x     = (const float*)d_in[0];
  const int*   ei    = (const int*)d_in[1];   // [2, E]
  const int*   et    = (const int*)d_in[2];   // [E]
  const float* pe    = (const float*)d_in[3];
  const float* W     = (const float*)d_in[4];
  const float* att_s = (const float*)d_in[5];
  const float* att_d = (const float*)d_in[6];
  const float* bias  = (const float*)d_in[7];
  float* out = (float*)d_out;

  // workspace carve-up (u32 units). xh is 256B-aligned (rows = 2 cache lines, not 3).
  size_t o = 0;
  int*      btail   = (int*)d_ws;                     o += 1024;          // 2*NB (pad)
  int*      row_dst = (int*)d_ws + o;                 o += N_NODES + 8;   // N+1 (pad)
  unsigned* Bh      = (unsigned*)d_ws + o;            o += 8192;
  float*    a_src   = (float*)((unsigned*)d_ws + o);  o += (size_t)(N_NODES + 1) * 4;
  float*    a_dst   = (float*)((unsigned*)d_ws + o);  o += (size_t)N_NODES * 4;
  o = (o + 63) & ~(size_t)63;                         // 256B-align xh
  unsigned* xh      = (unsigned*)d_ws + o;            o += (size_t)(N_NODES + 1) * 64;
  unsigned* bbuf    = (unsigned*)d_ws + o;            o += (size_t)2 * NB * BCAP;
  unsigned short* lst = (unsigned short*)((unsigned*)d_ws + o);  // LST_LEN+32 u16

  const int B = 256;

  hipMemsetAsync(btail, 0, 1024 * sizeof(int), stream);
  k_hist_prep<<<HIST_BLOCKS + 8, B, 0, stream>>>(ei, et, pe, W, Bh, btail, bbuf,
                                                 a_src, xh, lst);
  k_passB<<<2 * NB, B, 0, stream>>>(bbuf, btail, row_dst, lst,
                                    x, Bh, att_s, att_d, a_src, a_dst, xh);
  k_aggregate<<<ceil_div(N_NODES * 64, B), B, 0, stream>>>(row_dst, lst, a_src, a_dst,
                                                           xh, bias, out);
}